// Round 9
// baseline (1300.021 us; speedup 1.0000x reference)
//
#include <hip/hip_runtime.h>
#include <hip/hip_bf16.h>

// CfC cell via three bf16 MFMA GEMMs. Block = 256 thr = 4 waves (2Mx2N),
// tile 256x128, per-wave 128x64 (acc[8][4]). A+B staged via global_load_lds
// into THREE rotating slabs (A 16KB + B 8KB = 24KB/slab, 72KB total) ->
// TWO independent blocks per CU (the desync mechanism: one block's MFMA
// overlaps the other's LDS drain / pipeline fill). Depth-2 prefetch,
// counted vmcnt(6); st_16x32 swizzle; setprio MFMA.

typedef unsigned short u16;
typedef __bf16 bf16x8_t __attribute__((ext_vector_type(8)));
typedef float f32x4_t __attribute__((ext_vector_type(4)));
typedef u16 u16x8_t __attribute__((ext_vector_type(8)));

#define M_TOTAL 131072  // B*T = 128*1024

__device__ __forceinline__ u16 f2bf(float f) {
  union { float f; unsigned u; } v; v.f = f;
  unsigned r = v.u + 0x7FFFu + ((v.u >> 16) & 1u);  // RNE
  return (u16)(r >> 16);
}

__device__ __forceinline__ float fast_tanh(float x) {
  x = fminf(15.f, fmaxf(-15.f, x));
  float e = __expf(2.f * x);
  return (e - 1.f) * __builtin_amdgcn_rcpf(e + 1.f);
}

__device__ __forceinline__ float fast_sigmoid(float x) {
  return __builtin_amdgcn_rcpf(1.f + __expf(-x));
}

__device__ __forceinline__ void gload_lds16(const void* g, void* l) {
  __builtin_amdgcn_global_load_lds(
      (const __attribute__((address_space(1))) unsigned int*)g,
      (__attribute__((address_space(3))) unsigned int*)l,
      16, 0, 0);
}

// ---------------- prep kernels ----------------

__global__ void prep_x(const float* __restrict__ inp, const float* __restrict__ hx,
                       u16* __restrict__ X) {
  const int total = M_TOTAL * 96;
  int stride = gridDim.x * blockDim.x;
  for (int v = blockIdx.x * blockDim.x + threadIdx.x; v < total; v += stride) {
    int m = v / 96; int c = v - m * 96;
    const float* src = (c < 32) ? (inp + (size_t)m * 256 + (c << 3))
                                : (hx + (size_t)m * 512 + ((size_t)(c - 32) << 3));
    f32x4_t a = *(const f32x4_t*)src;
    f32x4_t b = *(const f32x4_t*)(src + 4);
    u16x8_t o;
    o[0]=f2bf(a[0]); o[1]=f2bf(a[1]); o[2]=f2bf(a[2]); o[3]=f2bf(a[3]);
    o[4]=f2bf(b[0]); o[5]=f2bf(b[1]); o[6]=f2bf(b[2]); o[7]=f2bf(b[3]);
    *(u16x8_t*)(X + (size_t)m * 768 + (c << 3)) = o;
  }
}

// all weight transposes ([n][k] row-major) + head-interleave + bias interleave
__global__ void prep_w(const float* __restrict__ W0, const float* __restrict__ W1,
                       const float* __restrict__ Wf1, const float* __restrict__ Wf2,
                       const float* __restrict__ Wta, const float* __restrict__ Wtb,
                       const float* __restrict__ bf1, const float* __restrict__ bf2,
                       const float* __restrict__ bta, const float* __restrict__ btb,
                       u16* __restrict__ W0T, u16* __restrict__ W1T,
                       u16* __restrict__ WhT, float* __restrict__ biasi) {
  int id = blockIdx.x * blockDim.x + threadIdx.x;
  u16x8_t o;
  if (id < 98304) {                       // W0T[n][k] = W0[k][n], K=768
    int n = id / 96, k0 = (id - n * 96) << 3;
#pragma unroll
    for (int i = 0; i < 8; ++i) o[i] = f2bf(W0[(size_t)(k0 + i) * 1024 + n]);
    *(u16x8_t*)(W0T + (size_t)n * 768 + k0) = o;
  } else if (id < 229376) {               // W1T[n][k] = W1[k][n], K=1024
    int id2 = id - 98304; int n = id2 >> 7, k0 = (id2 & 127) << 3;
#pragma unroll
    for (int i = 0; i < 8; ++i) o[i] = f2bf(W1[(size_t)(k0 + i) * 1024 + n]);
    *(u16x8_t*)(W1T + (size_t)n * 1024 + k0) = o;
  } else if (id < 491520) {               // WhT head-interleaved per 16-col block
    int id3 = id - 229376; int head = id3 >> 16; int id4 = id3 & 65535;
    int n = id4 >> 7, k0 = (id4 & 127) << 3;
    const float* W = (head == 0) ? Wf1 : (head == 1) ? Wf2 : (head == 2) ? Wta : Wtb;
#pragma unroll
    for (int i = 0; i < 8; ++i) o[i] = f2bf(W[(size_t)(k0 + i) * 512 + n]);
    int row = ((n >> 4) << 6) + head * 16 + (n & 15);
    *(u16x8_t*)(WhT + (size_t)row * 1024 + k0) = o;
  } else if (id < 492032) {               // interleaved head bias
    int h = id - 491520;
    int base = ((h >> 4) << 6) + (h & 15);
    biasi[base +  0] = bf1[h];
    biasi[base + 16] = bf2[h];
    biasi[base + 32] = bta[h];
    biasi[base + 48] = btb[h];
  }
}

// ---------------- 256x128 GEMM, 3-slab pipeline, 2 blocks/CU ----------------

#define BARX()   do { __builtin_amdgcn_s_barrier(); __builtin_amdgcn_sched_barrier(0); } while(0)
#define LGKM0()  do { asm volatile("s_waitcnt lgkmcnt(0)" ::: "memory"); __builtin_amdgcn_sched_barrier(0); } while(0)
#define SCHEDB() __builtin_amdgcn_sched_barrier(0)
#define WAITVM_(n) do { asm volatile("s_waitcnt vmcnt(" #n ")" ::: "memory"); __builtin_amdgcn_sched_barrier(0); } while(0)
#define WAITVM(n) WAITVM_(n)

template<int K, int NI, int EPI>
__global__ __launch_bounds__(256, 2)
void gemmR(const u16* __restrict__ A, const u16* __restrict__ BT,
           const float* __restrict__ bias, const float* __restrict__ ts,
           void* __restrict__ Cout)
{
  constexpr int NTn = NI / 128;
  constexpr int NT = K / 32;                   // 32-k steps
  constexpr int NWG = (M_TOTAL / 256) * NTn;
  constexpr int JMAIN = (NT == 24) ? 21 : 30;  // multiple of 3, <= NT-2
  __shared__ __align__(16) char smem[73728];   // 3 slabs x (A 16KB + B 8KB)

  const int bid = ((blockIdx.x & 7) * (NWG >> 3)) + (blockIdx.x >> 3);  // XCD swizzle
  const int mt = bid / NTn, nt = bid % NTn;
  const int tileM = mt * 256, tileN = nt * 128;

  const int tid = threadIdx.x, w = tid >> 6, l = tid & 63;
  const int wm = w >> 1, wn = w & 1;

  // staging (st_16x32: linear LDS dest + inverse-swizzled global k-offset)
  const int laneK = ((l & 3) << 3) ^ (((l >> 5) & 1) << 4);   // u16 units
  // A: wave w stages rows 64w..64w+63 (4 chunks of 16 rows / 1KB)
  const u16* aS = A + (size_t)(tileM + 64 * w + (l >> 2)) * K + laneK;
  // B: wave w stages rows 32w..32w+31 (2 chunks)
  const u16* bS = BT + (size_t)(tileN + 32 * w + (l >> 2)) * K + laneK;
  char* ldsA = smem + (w << 12);            // + slab*24576, chunks +0..+3KB
  char* ldsB = smem + 16384 + (w << 11);    // + slab*24576, chunks +0,+1KB

  // fragment reads (swizzle applied on read)
  const int colRs = ((l >> 4) << 4) ^ (((l >> 3) & 1) << 5);
  const char* aRd = smem + (wm * 128 + (l & 15)) * 64 + colRs;
  const char* bRd = smem + 16384 + (wn * 64 + (l & 15)) * 64 + colRs;

  f32x4_t acc[8][4];
#pragma unroll
  for (int i = 0; i < 8; ++i)
#pragma unroll
    for (int j = 0; j < 4; ++j) acc[i][j] = f32x4_t{0.f, 0.f, 0.f, 0.f};

  bf16x8_t af[8], bfr[4];
  int kOff = 0;  // k-elem offset of next slab to stage

#define STAGE6(SLOT) do { \
    gload_lds16(aS + kOff,          ldsA + (SLOT) * 24576); \
    gload_lds16(aS + kOff + 16 * K, ldsA + (SLOT) * 24576 + 1024); \
    gload_lds16(aS + kOff + 32 * K, ldsA + (SLOT) * 24576 + 2048); \
    gload_lds16(aS + kOff + 48 * K, ldsA + (SLOT) * 24576 + 3072); \
    gload_lds16(bS + kOff,          ldsB + (SLOT) * 24576); \
    gload_lds16(bS + kOff + 16 * K, ldsB + (SLOT) * 24576 + 1024); \
    kOff += 32; } while(0)

#define STEP(SLOT, STSLOT, WVN, DOST) do { \
    WAITVM(WVN); BARX(); \
    if (DOST) STAGE6(STSLOT); \
    _Pragma("unroll") for (int m_ = 0; m_ < 8; ++m_) \
      af[m_] = *(const bf16x8_t*)(aRd + (SLOT) * 24576 + m_ * 1024); \
    _Pragma("unroll") for (int n_ = 0; n_ < 4; ++n_) \
      bfr[n_] = *(const bf16x8_t*)(bRd + (SLOT) * 24576 + n_ * 1024); \
    LGKM0(); \
    __builtin_amdgcn_s_setprio(1); \
    _Pragma("unroll") for (int m_ = 0; m_ < 8; ++m_) \
      _Pragma("unroll") for (int n_ = 0; n_ < 4; ++n_) \
        acc[m_][n_] = __builtin_amdgcn_mfma_f32_16x16x32_bf16( \
            af[m_], bfr[n_], acc[m_][n_], 0, 0, 0); \
    __builtin_amdgcn_s_setprio(0); \
  } while(0)

  // prologue: stage slabs 0,1 (12 loads)
  STAGE6(0); STAGE6(1);

  // main: JMAIN steps in triples; every step stages (j+2) -> slot (j+2)%3
#pragma unroll 1
  for (int it = 0; it < JMAIN / 3; ++it) {
    STEP(0, 2, 6, true);
    STEP(1, 0, 6, true);
    STEP(2, 1, 6, true);
  }
  // peel
  if constexpr (NT == 24) {
    STEP(0, 2, 6, true);    // j=21, stages k-tile 23 -> slot 2
    STEP(1, 0, 6, false);   // j=22
    STEP(2, 0, 0, false);   // j=23
  } else {                  // NT == 32
    STEP(0, 0, 6, false);   // j=30
    STEP(1, 0, 0, false);   // j=31
  }

  // ---------------- epilogue (no LDS use) ----------------
  // C/D layout: col = lane&15, row = (lane>>4)*4 + reg (m89-verified)
  const int colBase = tileN + wn * 64 + (l & 15);
  float bv[4];
  bv[0] = bias[colBase];      bv[1] = bias[colBase + 16];
  bv[2] = bias[colBase + 32]; bv[3] = bias[colBase + 48];

  if constexpr (EPI == 0) {
    u16* C = (u16*)Cout;
    const int rowB = tileM + wm * 128 + ((l >> 4) << 2);
#pragma unroll
    for (int m = 0; m < 8; ++m)
#pragma unroll
      for (int nn = 0; nn < 4; ++nn)
#pragma unroll
        for (int j = 0; j < 4; ++j) {
          float v = acc[m][nn][j] + bv[nn];
          float t = 1.7159f * fast_tanh(0.666f * v);
          C[(size_t)(rowB + m * 16 + j) * NI + colBase + nn * 16] = f2bf(t);
        }
  } else {
    // heads interleaved per 16-col block: nn == head
    const int hg = ((tileN + wn * 64) >> 6) * 16 + (l & 15);
    float* out = (float*)Cout;
#pragma unroll
    for (int m = 0; m < 8; ++m)
#pragma unroll
      for (int j = 0; j < 4; ++j) {
        const int rl = wm * 128 + m * 16 + ((l >> 4) << 2) + j;
        const float tsv = ts[tileM + rl];   // L1 broadcast hit
        float ff1 = fast_tanh(acc[m][0][j] + bv[0]);
        float ff2 = fast_tanh(acc[m][1][j] + bv[1]);
        float s = fast_sigmoid((acc[m][2][j] + bv[2]) * tsv + (acc[m][3][j] + bv[3]));
        out[(size_t)(tileM + rl) * 512 + hg] = ff1 + s * (ff2 - ff1);
      }
  }
#undef STAGE6
#undef STEP
}

// ---------------- launch ----------------

extern "C" void kernel_launch(void* const* d_in, const int* in_sizes, int n_in,
                              void* d_out, int out_size, void* d_ws, size_t ws_size,
                              hipStream_t stream) {
  const float* input = (const float*)d_in[0];
  const float* hx    = (const float*)d_in[1];
  const float* ts    = (const float*)d_in[2];
  const float* W0    = (const float*)d_in[3];
  const float* b0    = (const float*)d_in[4];
  const float* W1    = (const float*)d_in[5];
  const float* b1    = (const float*)d_in[6];
  const float* Wff1  = (const float*)d_in[7];
  const float* bff1  = (const float*)d_in[8];
  const float* Wff2  = (const float*)d_in[9];
  const float* bff2  = (const float*)d_in[10];
  const float* Wta   = (const float*)d_in[11];
  const float* bta   = (const float*)d_in[12];
  const float* Wtb   = (const float*)d_in[13];
  const float* btb   = (const float*)d_in[14];

  const size_t WS_NEEDED = 544743424ull;
  if (ws_size < WS_NEEDED) return;
  char* ws = (char*)d_ws;
  u16* Xcat = (u16*)(ws);                      // [M,768] bf16, reused as X2 [M,1024]
  u16* X2   = (u16*)(ws);
  u16* X1   = (u16*)(ws + 268435456ull);       // [M,1024] bf16
  u16* W0T  = (u16*)(ws + 536870912ull);       // [1024][768]
  u16* W1T  = (u16*)(ws + 538443776ull);       // [1024][1024]
  u16* WhT  = (u16*)(ws + 540540928ull);       // [2048][1024] head-interleaved
  float* biasi = (float*)(ws + 544735232ull);  // [2048]

  prep_x<<<2048, 256, 0, stream>>>(input, hx, Xcat);
  prep_w<<<1922, 256, 0, stream>>>(W0, W1, Wff1, Wff2, Wta, Wtb,
                                   bff1, bff2, bta, btb, W0T, W1T, WhT, biasi);

  gemmR<768, 1024, 0><<<4096, 256, 0, stream>>>(Xcat, W0T, b0, nullptr, X1);
  gemmR<1024, 1024, 0><<<4096, 256, 0, stream>>>(X1, W1T, b1, nullptr, X2);
  gemmR<1024, 2048, 1><<<8192, 256, 0, stream>>>(X2, WhT, biasi, ts, d_out);
}